// Round 6
// baseline (266.778 us; speedup 1.0000x reference)
//
#include <hip/hip_runtime.h>
#include <hip/hip_bf16.h>
#include <stdint.h>

#define D_DIM 2048
#define B_DIM 1024
#define N_TOT 3072
#define NCLS 64
#define NB128 (N_TOT / 128)   // 24 tiles per side
#define MARGIN_F 0.8f
#define BIG_F 1e30f

typedef float f32x4 __attribute__((ext_vector_type(4)));
typedef int   i32x4 __attribute__((ext_vector_type(4)));
typedef __bf16 bf16x8 __attribute__((ext_vector_type(8)));

// async global->LDS, 16B per lane. LDS dest is wave-uniform base + lane*16;
// global src is per-lane. (m97 staging pattern.)
__device__ __forceinline__ void gld_lds16(const __bf16* g, __bf16* l) {
    __builtin_amdgcn_global_load_lds(
        (const __attribute__((address_space(1))) void*)g,
        (__attribute__((address_space(3))) void*)l,
        16, 0, 0);
}

// ---------------- reduction helpers ----------------
__device__ inline float block_reduce_sum(float v, float* sred) {
    int tid = threadIdx.x;
    sred[tid] = v; __syncthreads();
    for (int s = 128; s > 0; s >>= 1) {
        if (tid < s) sred[tid] = sred[tid] + sred[tid + s];
        __syncthreads();
    }
    float r = sred[0]; __syncthreads();
    return r;
}
__device__ inline float block_reduce_max(float v, float* sred) {
    int tid = threadIdx.x;
    sred[tid] = v; __syncthreads();
    for (int s = 128; s > 0; s >>= 1) {
        if (tid < s) sred[tid] = fmaxf(sred[tid], sred[tid + s]);
        __syncthreads();
    }
    float r = sred[0]; __syncthreads();
    return r;
}
__device__ inline float block_reduce_min(float v, float* sred) {
    int tid = threadIdx.x;
    sred[tid] = v; __syncthreads();
    for (int s = 128; s > 0; s >>= 1) {
        if (tid < s) sred[tid] = fminf(sred[tid], sred[tid + s]);
        __syncthreads();
    }
    float r = sred[0]; __syncthreads();
    return r;
}
__device__ inline float block_sum4(float v, float* tmp4, int lane, int wave) {
    #pragma unroll
    for (int off = 32; off > 0; off >>= 1) v += __shfl_down(v, off);
    __syncthreads();
    if (lane == 0) tmp4[wave] = v;
    __syncthreads();
    return tmp4[0] + tmp4[1] + tmp4[2] + tmp4[3];
}

__device__ inline int label_of(int j, const int* __restrict__ albl, const int* __restrict__ nlbl) {
    return (j < 2 * B_DIM) ? albl[j & (B_DIM - 1)] : nlbl[j - 2 * B_DIM];
}

__device__ inline float sq8(f32x4 a, f32x4 b) {
    return a[0]*a[0] + a[1]*a[1] + a[2]*a[2] + a[3]*a[3]
         + b[0]*b[0] + b[1]*b[1] + b[2]*b[2] + b[3]*b[3];
}
__device__ inline void st_bf8(__bf16* dst, f32x4 v0, f32x4 v1) {
    bf16x8 o;
    o[0] = (__bf16)v0[0]; o[1] = (__bf16)v0[1]; o[2] = (__bf16)v0[2]; o[3] = (__bf16)v0[3];
    o[4] = (__bf16)v1[0]; o[5] = (__bf16)v1[1]; o[6] = (__bf16)v1[2]; o[7] = (__bf16)v1[3];
    *(bf16x8*)dst = o;
}

// ---------------- 0: zero accumulators + pack labels ----------------
__global__ __launch_bounds__(256) void zero_kernel(
        float* __restrict__ T, float* __restrict__ scal,
        const int* __restrict__ albl, const int* __restrict__ nlbl, int* __restrict__ lab) {
    int t = blockIdx.x * 256 + threadIdx.x;
    if (t < NCLS * NCLS) T[t] = 0.f;
    if (t < 8) scal[t] = 0.f;
    if (t < N_TOT) lab[t] = label_of(t, albl, nlbl);
}

// ---------------- 1: fused prep: bf16 convert + norms + exact triplet term ----------------
__global__ __launch_bounds__(256) void prep_kernel(
        const float* __restrict__ A, const float* __restrict__ P, const float* __restrict__ Ng,
        __bf16* __restrict__ Eb, float* __restrict__ norms, float* __restrict__ scal) {
    __shared__ float tmp4[4];
    int i = blockIdx.x, tid = threadIdx.x;
    int lane = tid & 63, wave = tid >> 6;
    const f32x4* a4 = (const f32x4*)(A + (size_t)i * D_DIM);
    const f32x4* p4 = (const f32x4*)(P + (size_t)i * D_DIM);
    const f32x4* n4 = (const f32x4*)(Ng + (size_t)i * D_DIM);
    f32x4 av0 = a4[tid * 2], av1 = a4[tid * 2 + 1];
    f32x4 pv0 = p4[tid * 2], pv1 = p4[tid * 2 + 1];
    f32x4 nv0 = n4[tid * 2], nv1 = n4[tid * 2 + 1];
    float sa = sq8(av0, av1), sp = sq8(pv0, pv1), sn = sq8(nv0, nv1);
    f32x4 dp0 = av0 - pv0, dp1 = av1 - pv1;
    f32x4 dn0 = av0 - nv0, dn1 = av1 - nv1;
    float pd = sq8(dp0, dp1), nd = sq8(dn0, dn1);
    st_bf8(Eb + (size_t)i * D_DIM + tid * 8, av0, av1);
    st_bf8(Eb + (size_t)(B_DIM + i) * D_DIM + tid * 8, pv0, pv1);
    st_bf8(Eb + (size_t)(2 * B_DIM + i) * D_DIM + tid * 8, nv0, nv1);
    float saT = block_sum4(sa, tmp4, lane, wave);
    float spT = block_sum4(sp, tmp4, lane, wave);
    float snT = block_sum4(sn, tmp4, lane, wave);
    float pdT = block_sum4(pd, tmp4, lane, wave);
    float ndT = block_sum4(nd, tmp4, lane, wave);
    if (tid == 0) {
        norms[i] = saT;
        norms[B_DIM + i] = spT;
        norms[2 * B_DIM + i] = snT;
        atomicAdd(&scal[0], fmaxf(pdT - ndT + MARGIN_F, 0.f));
    }
}

// ---------------- 2: bf16 MFMA Gram, upper triangle, global_load_lds staging (m97 structure) ----
// 128x128 tile, BK=32, 4 waves; LDS linear [128][32] bf16 (required by global_load_lds:
// dest = wave-uniform base + lane*16). Each wave stages 32 rows of A and B per K-step
// with 2+2 width-16 async loads; 2-barrier loop; 16 MFMA per K-step per wave.
__global__ __launch_bounds__(256) void gram_gemm(const __bf16* __restrict__ Eb, float* __restrict__ G) {
    __shared__ __bf16 As[128 * 32] __attribute__((aligned(16)));
    __shared__ __bf16 Bs[128 * 32] __attribute__((aligned(16)));
    int tid = threadIdx.x, lane = tid & 63, wave = tid >> 6;
    int by = 0, rem = blockIdx.x;
    while (rem >= NB128 - by) { rem -= (NB128 - by); ++by; }
    int bx = by + rem;
    size_t row0 = (size_t)by * 128, col0 = (size_t)bx * 128;
    int wr = wave >> 1, wc = wave & 1;
    f32x4 acc[4][4];
    #pragma unroll
    for (int m = 0; m < 4; ++m)
        #pragma unroll
        for (int n = 0; n < 4; ++n) acc[m][n] = (f32x4){0.f, 0.f, 0.f, 0.f};

    int rl = lane & 15;
    int kg = (lane >> 4) * 8;                      // fragment k-offset (elems)
    // staging: lane covers row (lane>>2), col (lane&3)*8 within a 16-row group
    int srow = lane >> 2, scol = (lane & 3) * 8;
    const __bf16* gA0 = Eb + (row0 + wave * 32 + srow) * D_DIM + scol;
    const __bf16* gA1 = gA0 + 16 * D_DIM;
    const __bf16* gB0 = Eb + (col0 + wave * 32 + srow) * D_DIM + scol;
    const __bf16* gB1 = gB0 + 16 * D_DIM;
    __bf16* lA0 = &As[(wave * 32) * 32];
    __bf16* lA1 = &As[(wave * 32 + 16) * 32];
    __bf16* lB0 = &Bs[(wave * 32) * 32];
    __bf16* lB1 = &Bs[(wave * 32 + 16) * 32];

    for (int k0 = 0; k0 < D_DIM; k0 += 32) {
        __syncthreads();                           // prev K-step's ds_reads done
        gld_lds16(gA0 + k0, lA0);
        gld_lds16(gA1 + k0, lA1);
        gld_lds16(gB0 + k0, lB0);
        gld_lds16(gB1 + k0, lB1);
        __syncthreads();                           // drains vmcnt: staging visible
        bf16x8 af[4], bf[4];
        #pragma unroll
        for (int m = 0; m < 4; ++m)
            af[m] = *(const bf16x8*)&As[(wr * 64 + m * 16 + rl) * 32 + kg];
        #pragma unroll
        for (int n = 0; n < 4; ++n)
            bf[n] = *(const bf16x8*)&Bs[(wc * 64 + n * 16 + rl) * 32 + kg];
        #pragma unroll
        for (int m = 0; m < 4; ++m)
            #pragma unroll
            for (int n = 0; n < 4; ++n)
                acc[m][n] = __builtin_amdgcn_mfma_f32_16x16x32_bf16(af[m], bf[n], acc[m][n], 0, 0, 0);
    }
    // C/D layout (HW-verified): col = lane&15, row = (lane>>4)*4 + reg
    int rg = (lane >> 4) * 4;
    #pragma unroll
    for (int m = 0; m < 4; ++m)
        #pragma unroll
        for (int n = 0; n < 4; ++n)
            #pragma unroll
            for (int r = 0; r < 4; ++r) {
                size_t row = row0 + wr * 64 + m * 16 + rg + r;
                size_t col = col0 + wc * 64 + n * 16 + rl;
                G[row * N_TOT + col] = acc[m][n][r];
            }
}

// ---------------- 3: mirror upper triangle into lower (64x64 LDS transpose tiles) ----------------
__global__ __launch_bounds__(256) void mirror_kernel(float* __restrict__ G) {
    __shared__ float s[64 * 65];
    int b = blockIdx.x;
    int p = b >> 2, q = b & 3;
    int bj = 0, rem = p;
    while (rem >= NB128 - 1 - bj) { rem -= (NB128 - 1 - bj); ++bj; }
    int bi = bj + 1 + rem;
    int ti = bi * 2 + (q >> 1), tj = bj * 2 + (q & 1);
    int tid = threadIdx.x;
    int c = tid & 63, r4 = tid >> 6;
    const float* src = G + ((size_t)tj * 64) * N_TOT + (size_t)ti * 64;
    float* dst = G + ((size_t)ti * 64) * N_TOT + (size_t)tj * 64;
    #pragma unroll
    for (int rr = 0; rr < 16; ++rr) {
        int row = rr * 4 + r4;
        s[row * 65 + c] = src[(size_t)row * N_TOT + c];
    }
    __syncthreads();
    #pragma unroll
    for (int rr = 0; rr < 16; ++rr) {
        int row = rr * 4 + r4;
        dst[(size_t)row * N_TOT + c] = s[c * 65 + row];
    }
}

// ---------------- 4: vectorized T-binning over all rows (2 rows/block) ----------------
// f32x4 G/norms + int4 labels: 4 dists + 4 LDS atomics per vec-op. Per-row 64-bin LDS
// accumulator, flushed with 64 global atomics per row.
__global__ __launch_bounds__(256) void tsumv_kernel(
        const float* __restrict__ G, const float* __restrict__ norms,
        const int* __restrict__ lab, float* __restrict__ T) {
    __shared__ float tl[2 * NCLS];
    int tid = threadIdx.x;
    int r0 = blockIdx.x * 2;
    if (tid < 2 * NCLS) tl[tid] = 0.f;
    __syncthreads();
    #pragma unroll
    for (int rr = 0; rr < 2; ++rr) {
        int r = r0 + rr;
        float nr = norms[r];
        const float* Grow = G + (size_t)r * N_TOT;
        float* bins = &tl[rr * NCLS];
        #pragma unroll
        for (int it = 0; it < 3; ++it) {
            int j = (tid + it * 256) * 4;
            f32x4 g = *(const f32x4*)&Grow[j];
            f32x4 nj = *(const f32x4*)&norms[j];
            i32x4 lj = *(const i32x4*)&lab[j];
            f32x4 d2 = nr + nj - 2.f * g;
            float d0 = sqrtf(fmaxf(d2[0], 1e-8f));
            float d1 = sqrtf(fmaxf(d2[1], 1e-8f));
            float dd2 = sqrtf(fmaxf(d2[2], 1e-8f));
            float d3 = sqrtf(fmaxf(d2[3], 1e-8f));
            atomicAdd(&bins[lj[0]], d0);
            atomicAdd(&bins[lj[1]], d1);
            atomicAdd(&bins[lj[2]], dd2);
            atomicAdd(&bins[lj[3]], d3);
        }
    }
    __syncthreads();
    if (tid < 2 * NCLS) {
        float v = tl[tid];
        if (v != 0.f) {
            int lr = lab[r0 + (tid >> 6)];
            atomicAdd(&T[lr * NCLS + (tid & 63)], v);
        }
    }
}

// ---------------- 5: vectorized mining + successor term (one block per anchor row) ----------------
__global__ __launch_bounds__(256) void minev_kernel(
        const float* __restrict__ G, const float* __restrict__ norms,
        const int* __restrict__ lab, float* __restrict__ scal) {
    __shared__ float dneg[N_TOT] __attribute__((aligned(16)));
    __shared__ float qlist[128];
    __shared__ float cpart[4 * 64];
    __shared__ float sred[256];
    __shared__ float acc2[2];
    __shared__ int pcount;
    int i = blockIdx.x, tid = threadIdx.x;
    int lane = tid & 63, wave = tid >> 6;
    if (tid == 0) { pcount = 0; acc2[0] = 0.f; acc2[1] = 0.f; }
    __syncthreads();
    int la = lab[i];
    float ni = norms[i];
    const float* Grow = G + (size_t)i * N_TOT;
    float hp = -BIG_F, hn = BIG_F;
    #pragma unroll
    for (int it = 0; it < 3; ++it) {
        int j = (tid + it * 256) * 4;
        f32x4 g = *(const f32x4*)&Grow[j];
        f32x4 nj = *(const f32x4*)&norms[j];
        i32x4 lj = *(const i32x4*)&lab[j];
        f32x4 d2 = ni + nj - 2.f * g;
        float d0 = sqrtf(fmaxf(d2[0], 1e-8f));
        float d1 = sqrtf(fmaxf(d2[1], 1e-8f));
        float dd2 = sqrtf(fmaxf(d2[2], 1e-8f));
        float d3 = sqrtf(fmaxf(d2[3], 1e-8f));
        bool n0 = lj[0] != la, n1 = lj[1] != la, n2 = lj[2] != la, n3 = lj[3] != la;
        f32x4 dn = { n0 ? d0 : BIG_F, n1 ? d1 : BIG_F, n2 ? dd2 : BIG_F, n3 ? d3 : BIG_F };
        *(f32x4*)&dneg[j] = dn;
        hn = fminf(hn, fminf(fminf(dn[0], dn[1]), fminf(dn[2], dn[3])));
        // positives are rare (~31/3072): scalar handling
        if (!n0 && j + 0 != i) { hp = fmaxf(hp, d0); int p = atomicAdd(&pcount, 1); if (p < 128) qlist[p] = d0; }
        if (!n1 && j + 1 != i) { hp = fmaxf(hp, d1); int p = atomicAdd(&pcount, 1); if (p < 128) qlist[p] = d1; }
        if (!n2 && j + 2 != i) { hp = fmaxf(hp, dd2); int p = atomicAdd(&pcount, 1); if (p < 128) qlist[p] = dd2; }
        if (!n3 && j + 3 != i) { hp = fmaxf(hp, d3); int p = atomicAdd(&pcount, 1); if (p < 128) qlist[p] = d3; }
    }
    float hpAll = block_reduce_max(hp, sred);
    float hnAll = block_reduce_min(hn, sred);   // barriers also publish dneg/qlist/pcount
    int P = min(pcount, 128);
    const int CH = N_TOT / 4;                   // 768 elements per wave
    for (int q0 = 0; q0 < P; q0 += 64) {
        int nq = min(64, P - q0);
        float q = (lane < nq) ? qlist[q0 + lane] : BIG_F;
        float c0 = BIG_F, c1 = BIG_F, c2 = BIG_F, c3 = BIG_F;
        const f32x4* dv = (const f32x4*)&dneg[wave * CH];
        #pragma unroll 4
        for (int k = 0; k < CH / 4; ++k) {
            f32x4 v = dv[k];                    // 16B broadcast
            c0 = fminf(c0, (v[0] > q) ? v[0] : BIG_F);
            c1 = fminf(c1, (v[1] > q) ? v[1] : BIG_F);
            c2 = fminf(c2, (v[2] > q) ? v[2] : BIG_F);
            c3 = fminf(c3, (v[3] > q) ? v[3] : BIG_F);
        }
        float c = fminf(fminf(c0, c1), fminf(c2, c3));
        cpart[wave * 64 + lane] = c;
        __syncthreads();
        if (wave == 0) {
            float cc = fminf(fminf(cpart[lane], cpart[64 + lane]),
                             fminf(cpart[128 + lane], cpart[192 + lane]));
            float s = 0.f, n = 0.f;
            if (lane < nq && cc < 1e29f) {
                float qq = qlist[q0 + lane];
                if (cc < qq + MARGIN_F) { s = qq - cc + MARGIN_F; n = 1.f; }
            }
            #pragma unroll
            for (int off = 32; off > 0; off >>= 1) {
                s += __shfl_down(s, off);
                n += __shfl_down(n, off);
            }
            if (lane == 0) { acc2[0] += s; acc2[1] += n; }
        }
        __syncthreads();
    }
    if (tid == 0) {
        if (P > 0 && hnAll < 1e29f) {
            atomicAdd(&scal[1], fmaxf(hpAll - hnAll + MARGIN_F, 0.f));
            atomicAdd(&scal[2], 1.f);
        }
        if (acc2[0] != 0.f || acc2[1] != 0.f) {
            atomicAdd(&scal[3], acc2[0]);
            atomicAdd(&scal[4], acc2[1]);
        }
    }
}

// ---------------- 6: finalize: counts, intra/inter, combine ----------------
__global__ __launch_bounds__(256) void finalize_kernel(
        const float* __restrict__ T, const int* __restrict__ albl, const int* __restrict__ nlbl,
        const float* __restrict__ scal, float* __restrict__ out) {
    __shared__ int counts[NCLS];
    __shared__ int inA[NCLS];
    __shared__ float sred[256];
    int tid = threadIdx.x;
    if (tid < NCLS) { counts[tid] = 0; inA[tid] = 0; }
    __syncthreads();
    for (int i = tid; i < B_DIM; i += 256) {
        atomicAdd(&counts[albl[i]], 2);
        inA[albl[i]] = 1;
        atomicAdd(&counts[nlbl[i]], 1);
    }
    __syncthreads();
    float intra = 0.f;
    if (tid < NCLS) {
        int c = tid;
        float cnt = (float)counts[c];
        if (inA[c] && counts[c] > 1)
            intra = T[c * NCLS + c] / fmaxf(cnt * (cnt - 1.f), 1.f);
    }
    float inter = 0.f;
    for (int x = tid; x < NCLS * NCLS; x += 256) {
        int c1 = x >> 6, c2 = x & 63;
        if (c1 < c2 && inA[c1] && inA[c2]) {
            float pn = (float)counts[c1] * (float)counts[c2];
            if (pn > 0.f) inter += fmaxf(MARGIN_F - T[x] / fmaxf(pn, 1.f), 0.f);
        }
    }
    float intraAll = block_reduce_sum(intra, sred);
    float interAll = block_reduce_sum(inter, sred);
    if (tid == 0) {
        float trip = scal[0] / (float)B_DIM;
        float hard = (scal[2] > 0.f) ? scal[1] / fmaxf(scal[2], 1.f) : 0.f;
        float sh   = (scal[4] > 0.f) ? scal[3] / fmaxf(scal[4], 1.f) : 0.f;
        out[0] = trip + hard + sh + 0.1f * intraAll + 0.1f * interAll;
    }
}

// ---------------- launch ----------------
extern "C" void kernel_launch(void* const* d_in, const int* in_sizes, int n_in,
                              void* d_out, int out_size, void* d_ws, size_t ws_size,
                              hipStream_t stream) {
    const float* A  = (const float*)d_in[0];
    const float* P  = (const float*)d_in[1];
    const float* Ng = (const float*)d_in[2];
    const int* albl = (const int*)d_in[3];
    const int* nlbl = (const int*)d_in[4];
    char* ws = (char*)d_ws;
    // workspace layout (bytes)
    __bf16* Eb   = (__bf16*)(ws);                     // 3072*2048*2 = 12,582,912
    float* G     = (float*)(ws + 12582912);           // 3072*3072*4 = 37,748,736
    float* norms = (float*)(ws + 50331648);           // 3072*4
    float* T     = (float*)(ws + 50343936);           // 64*64*4
    float* scal  = (float*)(ws + 50360320);           // 8 floats (32 B)
    int*   lab   = (int*)(ws + 50360352);             // 3072*4 packed labels
    float* out   = (float*)d_out;

    hipLaunchKernelGGL(zero_kernel, dim3(16), dim3(256), 0, stream, T, scal, albl, nlbl, lab);
    hipLaunchKernelGGL(prep_kernel, dim3(B_DIM), dim3(256), 0, stream, A, P, Ng, Eb, norms, scal);
    hipLaunchKernelGGL(gram_gemm, dim3(NB128 * (NB128 + 1) / 2), dim3(256), 0, stream, Eb, G);
    hipLaunchKernelGGL(mirror_kernel, dim3((NB128 * (NB128 - 1) / 2) * 4), dim3(256), 0, stream, G);
    hipLaunchKernelGGL(tsumv_kernel, dim3(N_TOT / 2), dim3(256), 0, stream, G, norms, lab, T);
    hipLaunchKernelGGL(minev_kernel, dim3(B_DIM), dim3(256), 0, stream, G, norms, lab, scal);
    hipLaunchKernelGGL(finalize_kernel, dim3(1), dim3(256), 0, stream, T, albl, nlbl, scal, out);
}

// Round 7
// 264.242 us; speedup vs baseline: 1.0096x; 1.0096x over previous
//
#include <hip/hip_runtime.h>
#include <hip/hip_bf16.h>
#include <stdint.h>

#define D_DIM 2048
#define B_DIM 1024
#define N_TOT 3072
#define NCLS 64
#define NB128 (N_TOT / 128)   // 24 tiles per side
#define MARGIN_F 0.8f
#define BIG_F 1e30f

typedef float f32x4 __attribute__((ext_vector_type(4)));
typedef int   i32x4 __attribute__((ext_vector_type(4)));
typedef __bf16 bf16x8 __attribute__((ext_vector_type(8)));

// async global->LDS, 16B per lane. LDS dest is wave-uniform base + lane*16;
// global src is per-lane. (m97 staging pattern.)
__device__ __forceinline__ void gld_lds16(const __bf16* g, __bf16* l) {
    __builtin_amdgcn_global_load_lds(
        (const __attribute__((address_space(1))) void*)g,
        (__attribute__((address_space(3))) void*)l,
        16, 0, 0);
}

// ---------------- reduction helpers (256-thread blocks) ----------------
__device__ inline float block_reduce_sum(float v, float* sred) {
    int tid = threadIdx.x;
    sred[tid] = v; __syncthreads();
    for (int s = 128; s > 0; s >>= 1) {
        if (tid < s) sred[tid] = sred[tid] + sred[tid + s];
        __syncthreads();
    }
    float r = sred[0]; __syncthreads();
    return r;
}
__device__ inline float block_sum4(float v, float* tmp4, int lane, int wave) {
    #pragma unroll
    for (int off = 32; off > 0; off >>= 1) v += __shfl_down(v, off);
    __syncthreads();
    if (lane == 0) tmp4[wave] = v;
    __syncthreads();
    return tmp4[0] + tmp4[1] + tmp4[2] + tmp4[3];
}
// ---------------- reduction helpers (512-thread blocks) ----------------
__device__ inline float br_max512(float v, float* sred) {
    int tid = threadIdx.x;
    sred[tid] = v; __syncthreads();
    for (int s = 256; s > 0; s >>= 1) {
        if (tid < s) sred[tid] = fmaxf(sred[tid], sred[tid + s]);
        __syncthreads();
    }
    float r = sred[0]; __syncthreads();
    return r;
}
__device__ inline float br_min512(float v, float* sred) {
    int tid = threadIdx.x;
    sred[tid] = v; __syncthreads();
    for (int s = 256; s > 0; s >>= 1) {
        if (tid < s) sred[tid] = fminf(sred[tid], sred[tid + s]);
        __syncthreads();
    }
    float r = sred[0]; __syncthreads();
    return r;
}

__device__ inline int label_of(int j, const int* __restrict__ albl, const int* __restrict__ nlbl) {
    return (j < 2 * B_DIM) ? albl[j & (B_DIM - 1)] : nlbl[j - 2 * B_DIM];
}

__device__ inline float sq8(f32x4 a, f32x4 b) {
    return a[0]*a[0] + a[1]*a[1] + a[2]*a[2] + a[3]*a[3]
         + b[0]*b[0] + b[1]*b[1] + b[2]*b[2] + b[3]*b[3];
}
__device__ inline void st_bf8(__bf16* dst, f32x4 v0, f32x4 v1) {
    bf16x8 o;
    o[0] = (__bf16)v0[0]; o[1] = (__bf16)v0[1]; o[2] = (__bf16)v0[2]; o[3] = (__bf16)v0[3];
    o[4] = (__bf16)v1[0]; o[5] = (__bf16)v1[1]; o[6] = (__bf16)v1[2]; o[7] = (__bf16)v1[3];
    *(bf16x8*)dst = o;
}

// ---------------- 0: zero accumulators + pack labels ----------------
__global__ __launch_bounds__(256) void zero_kernel(
        float* __restrict__ T, float* __restrict__ scal,
        const int* __restrict__ albl, const int* __restrict__ nlbl, int* __restrict__ lab) {
    int t = blockIdx.x * 256 + threadIdx.x;
    if (t < NCLS * NCLS) T[t] = 0.f;
    if (t < 8) scal[t] = 0.f;
    if (t < N_TOT) lab[t] = label_of(t, albl, nlbl);
}

// ---------------- 1: fused prep: bf16 convert + norms + exact triplet term ----------------
__global__ __launch_bounds__(256) void prep_kernel(
        const float* __restrict__ A, const float* __restrict__ P, const float* __restrict__ Ng,
        __bf16* __restrict__ Eb, float* __restrict__ norms, float* __restrict__ scal) {
    __shared__ float tmp4[4];
    int i = blockIdx.x, tid = threadIdx.x;
    int lane = tid & 63, wave = tid >> 6;
    const f32x4* a4 = (const f32x4*)(A + (size_t)i * D_DIM);
    const f32x4* p4 = (const f32x4*)(P + (size_t)i * D_DIM);
    const f32x4* n4 = (const f32x4*)(Ng + (size_t)i * D_DIM);
    f32x4 av0 = a4[tid * 2], av1 = a4[tid * 2 + 1];
    f32x4 pv0 = p4[tid * 2], pv1 = p4[tid * 2 + 1];
    f32x4 nv0 = n4[tid * 2], nv1 = n4[tid * 2 + 1];
    float sa = sq8(av0, av1), sp = sq8(pv0, pv1), sn = sq8(nv0, nv1);
    f32x4 dp0 = av0 - pv0, dp1 = av1 - pv1;
    f32x4 dn0 = av0 - nv0, dn1 = av1 - nv1;
    float pd = sq8(dp0, dp1), nd = sq8(dn0, dn1);
    st_bf8(Eb + (size_t)i * D_DIM + tid * 8, av0, av1);
    st_bf8(Eb + (size_t)(B_DIM + i) * D_DIM + tid * 8, pv0, pv1);
    st_bf8(Eb + (size_t)(2 * B_DIM + i) * D_DIM + tid * 8, nv0, nv1);
    float saT = block_sum4(sa, tmp4, lane, wave);
    float spT = block_sum4(sp, tmp4, lane, wave);
    float snT = block_sum4(sn, tmp4, lane, wave);
    float pdT = block_sum4(pd, tmp4, lane, wave);
    float ndT = block_sum4(nd, tmp4, lane, wave);
    if (tid == 0) {
        norms[i] = saT;
        norms[B_DIM + i] = spT;
        norms[2 * B_DIM + i] = snT;
        atomicAdd(&scal[0], fmaxf(pdT - ndT + MARGIN_F, 0.f));
    }
}

// ---------------- 2: bf16 MFMA Gram, upper triangle, global_load_lds staging (m97 structure) ----
__global__ __launch_bounds__(256) void gram_gemm(const __bf16* __restrict__ Eb, float* __restrict__ G) {
    __shared__ __bf16 As[128 * 32] __attribute__((aligned(16)));
    __shared__ __bf16 Bs[128 * 32] __attribute__((aligned(16)));
    int tid = threadIdx.x, lane = tid & 63, wave = tid >> 6;
    int by = 0, rem = blockIdx.x;
    while (rem >= NB128 - by) { rem -= (NB128 - by); ++by; }
    int bx = by + rem;
    size_t row0 = (size_t)by * 128, col0 = (size_t)bx * 128;
    int wr = wave >> 1, wc = wave & 1;
    f32x4 acc[4][4];
    #pragma unroll
    for (int m = 0; m < 4; ++m)
        #pragma unroll
        for (int n = 0; n < 4; ++n) acc[m][n] = (f32x4){0.f, 0.f, 0.f, 0.f};

    int rl = lane & 15;
    int kg = (lane >> 4) * 8;
    int srow = lane >> 2, scol = (lane & 3) * 8;
    const __bf16* gA0 = Eb + (row0 + wave * 32 + srow) * D_DIM + scol;
    const __bf16* gA1 = gA0 + 16 * D_DIM;
    const __bf16* gB0 = Eb + (col0 + wave * 32 + srow) * D_DIM + scol;
    const __bf16* gB1 = gB0 + 16 * D_DIM;
    __bf16* lA0 = &As[(wave * 32) * 32];
    __bf16* lA1 = &As[(wave * 32 + 16) * 32];
    __bf16* lB0 = &Bs[(wave * 32) * 32];
    __bf16* lB1 = &Bs[(wave * 32 + 16) * 32];

    for (int k0 = 0; k0 < D_DIM; k0 += 32) {
        __syncthreads();
        gld_lds16(gA0 + k0, lA0);
        gld_lds16(gA1 + k0, lA1);
        gld_lds16(gB0 + k0, lB0);
        gld_lds16(gB1 + k0, lB1);
        __syncthreads();
        bf16x8 af[4], bf[4];
        #pragma unroll
        for (int m = 0; m < 4; ++m)
            af[m] = *(const bf16x8*)&As[(wr * 64 + m * 16 + rl) * 32 + kg];
        #pragma unroll
        for (int n = 0; n < 4; ++n)
            bf[n] = *(const bf16x8*)&Bs[(wc * 64 + n * 16 + rl) * 32 + kg];
        #pragma unroll
        for (int m = 0; m < 4; ++m)
            #pragma unroll
            for (int n = 0; n < 4; ++n)
                acc[m][n] = __builtin_amdgcn_mfma_f32_16x16x32_bf16(af[m], bf[n], acc[m][n], 0, 0, 0);
    }
    int rg = (lane >> 4) * 4;
    #pragma unroll
    for (int m = 0; m < 4; ++m)
        #pragma unroll
        for (int n = 0; n < 4; ++n)
            #pragma unroll
            for (int r = 0; r < 4; ++r) {
                size_t row = row0 + wr * 64 + m * 16 + rg + r;
                size_t col = col0 + wc * 64 + n * 16 + rl;
                G[row * N_TOT + col] = acc[m][n][r];
            }
}

// ---------------- 3: mirror upper triangle into lower (64x64 LDS transpose tiles) ----------------
__global__ __launch_bounds__(256) void mirror_kernel(float* __restrict__ G) {
    __shared__ float s[64 * 65];
    int b = blockIdx.x;
    int p = b >> 2, q = b & 3;
    int bj = 0, rem = p;
    while (rem >= NB128 - 1 - bj) { rem -= (NB128 - 1 - bj); ++bj; }
    int bi = bj + 1 + rem;
    int ti = bi * 2 + (q >> 1), tj = bj * 2 + (q & 1);
    int tid = threadIdx.x;
    int c = tid & 63, r4 = tid >> 6;
    const float* src = G + ((size_t)tj * 64) * N_TOT + (size_t)ti * 64;
    float* dst = G + ((size_t)ti * 64) * N_TOT + (size_t)tj * 64;
    #pragma unroll
    for (int rr = 0; rr < 16; ++rr) {
        int row = rr * 4 + r4;
        s[row * 65 + c] = src[(size_t)row * N_TOT + c];
    }
    __syncthreads();
    #pragma unroll
    for (int rr = 0; rr < 16; ++rr) {
        int row = rr * 4 + r4;
        dst[(size_t)row * N_TOT + c] = s[c * 65 + row];
    }
}

// ---------------- 4: vectorized T-binning, rows B..N only (anchor rows binned in minev) ----------
__global__ __launch_bounds__(512) void tsumv_kernel(
        const float* __restrict__ G, const float* __restrict__ norms,
        const int* __restrict__ lab, float* __restrict__ T) {
    __shared__ float tl[2 * NCLS];
    int tid = threadIdx.x;
    int r0 = B_DIM + blockIdx.x * 2;
    if (tid < 2 * NCLS) tl[tid] = 0.f;
    __syncthreads();
    #pragma unroll
    for (int rr = 0; rr < 2; ++rr) {
        int r = r0 + rr;
        float nr = norms[r];
        const float* Grow = G + (size_t)r * N_TOT;
        float* bins = &tl[rr * NCLS];
        #pragma unroll
        for (int it = 0; it < 2; ++it) {
            int jv = tid + it * 512;
            if (jv * 4 < N_TOT) {
                int j = jv * 4;
                f32x4 g = *(const f32x4*)&Grow[j];
                f32x4 nj = *(const f32x4*)&norms[j];
                i32x4 lj = *(const i32x4*)&lab[j];
                f32x4 d2 = nr + nj - 2.f * g;
                atomicAdd(&bins[lj[0]], sqrtf(fmaxf(d2[0], 1e-8f)));
                atomicAdd(&bins[lj[1]], sqrtf(fmaxf(d2[1], 1e-8f)));
                atomicAdd(&bins[lj[2]], sqrtf(fmaxf(d2[2], 1e-8f)));
                atomicAdd(&bins[lj[3]], sqrtf(fmaxf(d2[3], 1e-8f)));
            }
        }
    }
    __syncthreads();
    if (tid < 2 * NCLS) {
        float v = tl[tid];
        if (v != 0.f) {
            int lr = lab[r0 + (tid >> 6)];
            atomicAdd(&T[lr * NCLS + (tid & 63)], v);
        }
    }
}

// ---------------- 5: mining + successor + anchor-row T-binning (512 threads = 8 waves) --------
// R6 diagnosis: all pipes <25%, occupancy 15% -> latency-bound at 16 waves/CU. Now 8 waves/block,
// 4 blocks/CU = 32 waves/CU (HW max). Also bins this anchor row's distances into T (64 LDS bins),
// letting tsumv skip rows 0..B-1.
__global__ __launch_bounds__(512) void minev_kernel(
        const float* __restrict__ G, const float* __restrict__ norms,
        const int* __restrict__ lab, float* __restrict__ T, float* __restrict__ scal) {
    __shared__ float dneg[N_TOT] __attribute__((aligned(16)));
    __shared__ float qlist[128];
    __shared__ float cpart[8 * 64];
    __shared__ float sred[512];
    __shared__ float tl[NCLS];
    __shared__ float acc2[2];
    __shared__ int pcount;
    int i = blockIdx.x, tid = threadIdx.x;
    int lane = tid & 63, wave = tid >> 6;
    if (tid == 0) { pcount = 0; acc2[0] = 0.f; acc2[1] = 0.f; }
    if (tid < NCLS) tl[tid] = 0.f;
    __syncthreads();
    int la = lab[i];
    float ni = norms[i];
    const float* Grow = G + (size_t)i * N_TOT;
    float hp = -BIG_F, hn = BIG_F;
    #pragma unroll
    for (int it = 0; it < 2; ++it) {
        int jv = tid + it * 512;
        if (jv * 4 < N_TOT) {
            int j = jv * 4;
            f32x4 g = *(const f32x4*)&Grow[j];
            f32x4 nj = *(const f32x4*)&norms[j];
            i32x4 lj = *(const i32x4*)&lab[j];
            f32x4 d2 = ni + nj - 2.f * g;
            float d0 = sqrtf(fmaxf(d2[0], 1e-8f));
            float d1 = sqrtf(fmaxf(d2[1], 1e-8f));
            float dd2 = sqrtf(fmaxf(d2[2], 1e-8f));
            float d3 = sqrtf(fmaxf(d2[3], 1e-8f));
            atomicAdd(&tl[lj[0]], d0);
            atomicAdd(&tl[lj[1]], d1);
            atomicAdd(&tl[lj[2]], dd2);
            atomicAdd(&tl[lj[3]], d3);
            bool n0 = lj[0] != la, n1 = lj[1] != la, n2 = lj[2] != la, n3 = lj[3] != la;
            f32x4 dn = { n0 ? d0 : BIG_F, n1 ? d1 : BIG_F, n2 ? dd2 : BIG_F, n3 ? d3 : BIG_F };
            *(f32x4*)&dneg[j] = dn;
            hn = fminf(hn, fminf(fminf(dn[0], dn[1]), fminf(dn[2], dn[3])));
            // positives are rare (~31/3072): scalar handling
            if (!n0 && j + 0 != i) { hp = fmaxf(hp, d0); int p = atomicAdd(&pcount, 1); if (p < 128) qlist[p] = d0; }
            if (!n1 && j + 1 != i) { hp = fmaxf(hp, d1); int p = atomicAdd(&pcount, 1); if (p < 128) qlist[p] = d1; }
            if (!n2 && j + 2 != i) { hp = fmaxf(hp, dd2); int p = atomicAdd(&pcount, 1); if (p < 128) qlist[p] = dd2; }
            if (!n3 && j + 3 != i) { hp = fmaxf(hp, d3); int p = atomicAdd(&pcount, 1); if (p < 128) qlist[p] = d3; }
        }
    }
    __syncthreads();
    if (tid < NCLS) {
        float v = tl[tid];
        if (v != 0.f) atomicAdd(&T[la * NCLS + tid], v);
    }
    float hpAll = br_max512(hp, sred);
    float hnAll = br_min512(hn, sred);   // barriers also publish dneg/qlist/pcount
    int P = min(pcount, 128);
    const int CH = N_TOT / 8;            // 384 elements per wave
    for (int q0 = 0; q0 < P; q0 += 64) {
        int nq = min(64, P - q0);
        float q = (lane < nq) ? qlist[q0 + lane] : BIG_F;
        float c0 = BIG_F, c1 = BIG_F, c2 = BIG_F, c3 = BIG_F;
        const f32x4* dv = (const f32x4*)&dneg[wave * CH];
        #pragma unroll 4
        for (int k = 0; k < CH / 4; ++k) {
            f32x4 v = dv[k];                    // 16B broadcast
            c0 = fminf(c0, (v[0] > q) ? v[0] : BIG_F);
            c1 = fminf(c1, (v[1] > q) ? v[1] : BIG_F);
            c2 = fminf(c2, (v[2] > q) ? v[2] : BIG_F);
            c3 = fminf(c3, (v[3] > q) ? v[3] : BIG_F);
        }
        float c = fminf(fminf(c0, c1), fminf(c2, c3));
        cpart[wave * 64 + lane] = c;
        __syncthreads();
        if (wave == 0) {
            float cc = cpart[lane];
            #pragma unroll
            for (int w = 1; w < 8; ++w) cc = fminf(cc, cpart[w * 64 + lane]);
            float s = 0.f, n = 0.f;
            if (lane < nq && cc < 1e29f) {
                float qq = qlist[q0 + lane];
                if (cc < qq + MARGIN_F) { s = qq - cc + MARGIN_F; n = 1.f; }
            }
            #pragma unroll
            for (int off = 32; off > 0; off >>= 1) {
                s += __shfl_down(s, off);
                n += __shfl_down(n, off);
            }
            if (lane == 0) { acc2[0] += s; acc2[1] += n; }
        }
        __syncthreads();
    }
    if (tid == 0) {
        if (P > 0 && hnAll < 1e29f) {
            atomicAdd(&scal[1], fmaxf(hpAll - hnAll + MARGIN_F, 0.f));
            atomicAdd(&scal[2], 1.f);
        }
        if (acc2[0] != 0.f || acc2[1] != 0.f) {
            atomicAdd(&scal[3], acc2[0]);
            atomicAdd(&scal[4], acc2[1]);
        }
    }
}

// ---------------- 6: finalize: counts, intra/inter, combine ----------------
__global__ __launch_bounds__(256) void finalize_kernel(
        const float* __restrict__ T, const int* __restrict__ albl, const int* __restrict__ nlbl,
        const float* __restrict__ scal, float* __restrict__ out) {
    __shared__ int counts[NCLS];
    __shared__ int inA[NCLS];
    __shared__ float sred[256];
    int tid = threadIdx.x;
    if (tid < NCLS) { counts[tid] = 0; inA[tid] = 0; }
    __syncthreads();
    for (int i = tid; i < B_DIM; i += 256) {
        atomicAdd(&counts[albl[i]], 2);
        inA[albl[i]] = 1;
        atomicAdd(&counts[nlbl[i]], 1);
    }
    __syncthreads();
    float intra = 0.f;
    if (tid < NCLS) {
        int c = tid;
        float cnt = (float)counts[c];
        if (inA[c] && counts[c] > 1)
            intra = T[c * NCLS + c] / fmaxf(cnt * (cnt - 1.f), 1.f);
    }
    float inter = 0.f;
    for (int x = tid; x < NCLS * NCLS; x += 256) {
        int c1 = x >> 6, c2 = x & 63;
        if (c1 < c2 && inA[c1] && inA[c2]) {
            float pn = (float)counts[c1] * (float)counts[c2];
            if (pn > 0.f) inter += fmaxf(MARGIN_F - T[x] / fmaxf(pn, 1.f), 0.f);
        }
    }
    float intraAll = block_reduce_sum(intra, sred);
    float interAll = block_reduce_sum(inter, sred);
    if (tid == 0) {
        float trip = scal[0] / (float)B_DIM;
        float hard = (scal[2] > 0.f) ? scal[1] / fmaxf(scal[2], 1.f) : 0.f;
        float sh   = (scal[4] > 0.f) ? scal[3] / fmaxf(scal[4], 1.f) : 0.f;
        out[0] = trip + hard + sh + 0.1f * intraAll + 0.1f * interAll;
    }
}

// ---------------- launch ----------------
extern "C" void kernel_launch(void* const* d_in, const int* in_sizes, int n_in,
                              void* d_out, int out_size, void* d_ws, size_t ws_size,
                              hipStream_t stream) {
    const float* A  = (const float*)d_in[0];
    const float* P  = (const float*)d_in[1];
    const float* Ng = (const float*)d_in[2];
    const int* albl = (const int*)d_in[3];
    const int* nlbl = (const int*)d_in[4];
    char* ws = (char*)d_ws;
    // workspace layout (bytes)
    __bf16* Eb   = (__bf16*)(ws);                     // 3072*2048*2 = 12,582,912
    float* G     = (float*)(ws + 12582912);           // 3072*3072*4 = 37,748,736
    float* norms = (float*)(ws + 50331648);           // 3072*4
    float* T     = (float*)(ws + 50343936);           // 64*64*4
    float* scal  = (float*)(ws + 50360320);           // 8 floats (32 B)
    int*   lab   = (int*)(ws + 50360352);             // 3072*4 packed labels
    float* out   = (float*)d_out;

    hipLaunchKernelGGL(zero_kernel, dim3(16), dim3(256), 0, stream, T, scal, albl, nlbl, lab);
    hipLaunchKernelGGL(prep_kernel, dim3(B_DIM), dim3(256), 0, stream, A, P, Ng, Eb, norms, scal);
    hipLaunchKernelGGL(gram_gemm, dim3(NB128 * (NB128 + 1) / 2), dim3(256), 0, stream, Eb, G);
    hipLaunchKernelGGL(mirror_kernel, dim3((NB128 * (NB128 - 1) / 2) * 4), dim3(256), 0, stream, G);
    hipLaunchKernelGGL(tsumv_kernel, dim3((N_TOT - B_DIM) / 2), dim3(512), 0, stream, G, norms, lab, T);
    hipLaunchKernelGGL(minev_kernel, dim3(B_DIM), dim3(512), 0, stream, G, norms, lab, T, scal);
    hipLaunchKernelGGL(finalize_kernel, dim3(1), dim3(256), 0, stream, T, albl, nlbl, scal, out);
}